// Round 2
// baseline (833.997 us; speedup 1.0000x reference)
//
#include <hip/hip_runtime.h>
#include <stdint.h>

typedef unsigned long long u64;
typedef unsigned int u32;

#define NND 20000      // nodes
#define EUA 160000     // directed input edges (2 * E_UND)
#define EFE 80000      // max clean (undirected, deduped) edges
#define ICH 128
#define HIDC 64
#define SCAN_BS 256
#define NB_N ((NND + 255) / 256)
#define NB_EU ((EUA + 255) / 256)
#define NB_EF ((EFE + 255) / 256)
#define NSCAN_B ((NND + SCAN_BS - 1) / SCAN_BS)
#define GEB 64         // edges per gemm block
#define XS_PAD 132     // xs leading-dim pad
#define BK64 64        // fixed bucket stride (degrees Poisson(4/8), max ~25)
#define SEL_BINS 4096  // 12-bit digits, 4 passes (keys: bit48==1 always)
#define FBLK 512       // persistent grid: 2 blocks/CU on 256 CUs (all resident)
#define CHAINS 4096    // moment-reduction chains (MUST stay 4096: bitwise-
                       // identical summation order vs the verified baseline)
#define VMAX ((EFE + CHAINS - 1) / CHAINS)  // 20 edges/chain -> registers

// scal slots: 0=E, 2=M, 3=Ep, 4=Ekept, 15=dummy

// ---------------- scan (exclusive, n = NND fixed; 2-dispatch) ----------------
__global__ void kScanA(const int* __restrict__ in, int* __restrict__ out,
                       int* __restrict__ bsums, int n) {
    __shared__ int sh[SCAN_BS];
    int tid = threadIdx.x;
    int i = blockIdx.x * SCAN_BS + tid;
    int v = (i < n) ? in[i] : 0;
    sh[tid] = v;
    __syncthreads();
    for (int o = 1; o < SCAN_BS; o <<= 1) {
        int t = (tid >= o) ? sh[tid - o] : 0;
        __syncthreads();
        sh[tid] += t;
        __syncthreads();
    }
    if (i < n) out[i] = sh[tid] - v;  // exclusive within block
    if (tid == SCAN_BS - 1) bsums[blockIdx.x] = sh[tid];
}
__global__ void kScanB(int* __restrict__ out, const int* __restrict__ bsums,
                       int n, int nb, int* __restrict__ totalDst) {
    __shared__ int sh[160];
    int tid = threadIdx.x;
    if (tid <= nb) sh[tid] = (tid < nb) ? bsums[tid] : 0;
    __syncthreads();
    if (tid == 0) {
        int acc = 0;
        for (int i = 0; i < nb; i++) { int t = sh[i]; sh[i] = acc; acc += t; }
        sh[nb] = acc;
    }
    __syncthreads();
    int i = blockIdx.x * SCAN_BS + tid;
    if (i < n) out[i] += sh[blockIdx.x];
    if (i == 0) {
        int tot = sh[nb];
        out[n] = tot;
        *totalDst = tot;
    }
}

// ---------------- clean edge build (stride-64 direct buckets) ----------------
__global__ void kFilterScatter64(const int* __restrict__ ei, int* __restrict__ cnt,
                                 int* __restrict__ bucketV) {
    int i = blockIdx.x * 256 + threadIdx.x;
    if (i >= EUA) return;
    int s = ei[i], d = ei[EUA + i];
    if (s < d) {
        int p = atomicAdd(&cnt[s], 1);
        bucketV[(s << 6) + p] = d;
    }
}
// wave-parallel rank sort per fixed-stride bucket + unique count
__global__ void kRankSort64(const int* __restrict__ in, int* __restrict__ out,
                            const int* __restrict__ lenA, int* __restrict__ ucnt) {
    int a = blockIdx.x;
    int len = lenA[a];
    int base = a << 6;
    for (int j = threadIdx.x; j < len; j += 64) {
        int v = in[base + j];
        int r = 0;
        for (int i = 0; i < len; i++) {
            int w = in[base + i];
            r += (w < v) || (w == v && i < j);
        }
        out[base + r] = v;
    }
    __syncthreads();
    int c = 0;
    for (int j = threadIdx.x; j < len; j += 64)
        c += (j == 0) || (out[base + j] != out[base + j - 1]);
#pragma unroll
    for (int o = 32; o > 0; o >>= 1) c += __shfl_down(c, o, 64);
    if (threadIdx.x == 0) ucnt[a] = c;
}
// compact (stride-64 in, contiguous sorted (u,v) out) + incidence count fused
__global__ void kCompactInc(const int* __restrict__ arr, const int* __restrict__ cnt,
                            const int* __restrict__ uoff, int* __restrict__ eU,
                            int* __restrict__ eV, int* __restrict__ icnt) {
    int u = blockIdx.x * 256 + threadIdx.x;
    if (u >= NND) return;
    int s = u << 6, e = s + cnt[u], o = uoff[u];
    int myc = 0;
    for (int i = s; i < e; i++)
        if (i == s || arr[i] != arr[i - 1]) {
            int v = arr[i];
            eU[o] = u; eV[o] = v; o++;
            atomicAdd(&icnt[v], 1);
            myc++;
        }
    if (myc) atomicAdd(&icnt[u], myc);
}

// ---------------- incidence (stride-64) scatter + dinv fused ----------------
__global__ void kIncScatterDinv64(const int* __restrict__ eU, const int* __restrict__ eV,
                                  const int* __restrict__ scal, int* __restrict__ itmp,
                                  int* __restrict__ ilist, const int* __restrict__ icnt,
                                  float* __restrict__ dinv) {
    int e = blockIdx.x * 256 + threadIdx.x;
    if (e >= scal[0]) return;
    int u = eU[e], v = eV[e];
    ilist[(u << 6) + atomicAdd(&itmp[u], 1)] = e;
    ilist[(v << 6) + atomicAdd(&itmp[v], 1)] = e;
    dinv[e] = rsqrtf((float)(icnt[u] + icnt[v] - 1));
}

// ---------------- GEMM: h = (0.5*(x[u]+x[v])) @ W1 ----------------
__global__ void kGemm(const float* __restrict__ x, const float* __restrict__ W1,
                      const int* __restrict__ eU, const int* __restrict__ eV,
                      const int* __restrict__ scal, float* __restrict__ h) {
    __shared__ float W1s[ICH][HIDC];
    __shared__ float xs[GEB][XS_PAD];
    int t = threadIdx.x;
    int E = scal[0];
    int e0 = blockIdx.x * GEB;
    if (e0 >= E) return;

    {
        const float4* Wv = (const float4*)W1;
        float4* Ws = (float4*)&W1s[0][0];
        for (int i = t; i < ICH * HIDC / 4; i += 256) Ws[i] = Wv[i];
    }
    {
        int eb = t >> 2, q = t & 3;
        int e = e0 + eb;
        if (e < E) {
            int u = eU[e], v = eV[e];
            const float4* xu = (const float4*)(x + (size_t)u * ICH) + q * 8;
            const float4* xv = (const float4*)(x + (size_t)v * ICH) + q * 8;
            float* xd = &xs[eb][q * 32];
#pragma unroll
            for (int i = 0; i < 8; i++) {
                float4 a = xu[i], b = xv[i];
                xd[i * 4 + 0] = 0.5f * (a.x + b.x);
                xd[i * 4 + 1] = 0.5f * (a.y + b.y);
                xd[i * 4 + 2] = 0.5f * (a.z + b.z);
                xd[i * 4 + 3] = 0.5f * (a.w + b.w);
            }
        }
    }
    __syncthreads();

    int cg4 = (t & 15) * 4;
    int es = t >> 4;
    float a00=0,a01=0,a02=0,a03=0, a10=0,a11=0,a12=0,a13=0;
    float a20=0,a21=0,a22=0,a23=0, a30=0,a31=0,a32=0,a33=0;
#pragma unroll 4
    for (int k = 0; k < ICH; k++) {
        float4 wv = *(const float4*)&W1s[k][cg4];
        float x0 = xs[es][k], x1 = xs[es + 16][k];
        float x2 = xs[es + 32][k], x3 = xs[es + 48][k];
        a00 += x0 * wv.x; a01 += x0 * wv.y; a02 += x0 * wv.z; a03 += x0 * wv.w;
        a10 += x1 * wv.x; a11 += x1 * wv.y; a12 += x1 * wv.z; a13 += x1 * wv.w;
        a20 += x2 * wv.x; a21 += x2 * wv.y; a22 += x2 * wv.z; a23 += x2 * wv.w;
        a30 += x3 * wv.x; a31 += x3 * wv.y; a32 += x3 * wv.z; a33 += x3 * wv.w;
    }
    int e;
    e = e0 + es;
    if (e < E) *(float4*)&h[(size_t)e * HIDC + cg4] = make_float4(a00, a01, a02, a03);
    e = e0 + es + 16;
    if (e < E) *(float4*)&h[(size_t)e * HIDC + cg4] = make_float4(a10, a11, a12, a13);
    e = e0 + es + 32;
    if (e < E) *(float4*)&h[(size_t)e * HIDC + cg4] = make_float4(a20, a21, a22, a23);
    e = e0 + es + 48;
    if (e < E) *(float4*)&h[(size_t)e * HIDC + cg4] = make_float4(a30, a31, a32, a33);
}

// ---------------- radix select replay (4 passes x 12 bits) ------------------
__device__ __forceinline__ u64 selReplay(const int* __restrict__ histBase, int passes,
                                         int E, int t, int* aux, int* shTmp) {
    int kr = E / 2;
    if (kr > NND / 2) kr = NND / 2;
    if (kr < 1) kr = 1;
    u64 pref = 1ULL << 48;
    for (int q = 0; q < passes; q++) {
        int shift = 36 - 12 * q;
        const int* hq = histBase + q * SEL_BINS;
        int b[16];
        int g = 0;
#pragma unroll
        for (int j = 0; j < 16; j++) { b[j] = hq[16 * t + j]; g += b[j]; }
        aux[t] = g;
        __syncthreads();
        for (int o = 1; o < 256; o <<= 1) {
            int v = (t + o < 256) ? aux[t + o] : 0;
            __syncthreads();
            aux[t] += v;
            __syncthreads();
        }
        int suf = aux[t] - g;  // strictly-above my 16-bin group
        if (suf < kr && kr <= suf + g) {
            int cum = suf, found = 16 * t;
            for (int j = 15; j >= 0; j--) {
                int hc = b[j];
                if (cum + hc >= kr) { found = 16 * t + j; break; }
                cum += hc;
            }
            shTmp[0] = found;
            shTmp[1] = kr - cum;
        }
        __syncthreads();
        pref |= ((u64)shTmp[0]) << shift;
        kr = shTmp[1];
        __syncthreads();
    }
    return pref;
}

// ---------------- device-scope grid barrier ---------------------------------
// All FBLK=512 blocks are co-resident by construction (__launch_bounds__(256,2)
// => 2 blocks/CU * 256 CUs = 512). Release: __syncthreads drains the block's
// stores, thread0's __threadfence (agent fence -> L2 writeback) publishes them
// cross-XCD; arrival via device-scope atomicAdd. Acquire: RMW spin + agent
// fence (L1/L2 invalidate) + __syncthreads.
__device__ __forceinline__ void gsync(int* bar, int target) {
    __syncthreads();
    if (threadIdx.x == 0) {
        __threadfence();
        atomicAdd(bar, 1);
        while (atomicAdd(bar, 0) < target)
            __builtin_amdgcn_s_sleep(2);
        __threadfence();
    }
    __syncthreads();
}

// ---------------- fused mid-chain persistent kernel -------------------------
// Replaces: kSGather, kConv1Red1, kRed2, kNormZ, kS2, kScore, kHistR x3,
// kMinKey, kCluster (11 dispatches -> 1). The conv1-epilogue values live in
// registers (2 chains x VMAX=20 per thread) across the mean/var barrier, so
// h2 is never materialized (saves 41 MB of HBM traffic). All floating-point
// summation orders are BITWISE IDENTICAL to the verified multi-dispatch
// baseline (same 4096-chain decomposition, same quarter-sequential combine).
struct FParams {
    const float* h; const float* dinv; const int* icnt; const int* ilistS;
    const int* eU; const int* eV;
    const float* b1; const float* gamma1; const float* beta1;
    const float* W2; const float* b2;
    const int* scal;
    float* Snode; float* partial; float* partial2; float* miniP;  // miniP[8][64]
    float* z; float* S2; float* score;
    u64* okey; u64* minOkey; int* hist;  // hist: 4*SEL_BINS (pass-major)
    int* n2c; int* present; int* csize; int* cmemb;
    int* bar;
};

__global__ __launch_bounds__(256, 2) void kFusedMid(FParams P) {
    __shared__ int shHist[SEL_BINS];
    __shared__ int aux[256];
    __shared__ int shTmp[2];
    int t = threadIdx.x;
    int b = blockIdx.x;
    int gtid = b * 256 + t;
    int w = t >> 6, c = t & 63;
    int E = P.scal[0];
    int barPhase = 0;
#define GSYNC() do { barPhase += FBLK; gsync(P.bar, barPhase); } while (0)

    // ---- phase 0: Snode[n][c] = sum over incident edges (== kSGather) ----
    for (int id = gtid; id < NND * HIDC; id += FBLK * 256) {
        int n = id >> 6;                 // c stays id&63 == t&63 (stride mult of 64)
        int base = n << 6, len = P.icnt[n];
        float acc = 0.f;
        for (int j = 0; j < len; j++) {
            int ed = P.ilistS[base + j];
            acc += P.h[(size_t)ed * HIDC + c] * P.dinv[ed];
        }
        P.Snode[id] = acc;
    }
    GSYNC();

    // ---- phase 1: conv1 epilogue in regs + per-chain moments ----
    // wave handles chains cA=2*(b*4+w), cB=cA+1; per-chain edge order e =
    // chain + it*4096 -- identical to baseline kConv1Red1.
    int gw = b * 4 + w;                  // 0..2047
    int cA = 2 * gw, cB = cA + 1;
    float vA[VMAX], vB[VMAX];
    {
        float bc = P.b1[c];
        float accA = 0.f, acc2A = 0.f, accB = 0.f, acc2B = 0.f;
#pragma unroll
        for (int it = 0; it < VMAX; it++) {
            int eA = cA + it * CHAINS;
            if (eA < E) {
                float a = P.dinv[eA];
                float val = a * (P.Snode[(size_t)P.eU[eA] * HIDC + c] +
                                 P.Snode[(size_t)P.eV[eA] * HIDC + c]) -
                            a * a * P.h[(size_t)eA * HIDC + c] + bc;
                vA[it] = val; accA += val; acc2A += val * val;
            } else vA[it] = 0.f;
            int eB = cB + it * CHAINS;
            if (eB < E) {
                float a = P.dinv[eB];
                float val = a * (P.Snode[(size_t)P.eU[eB] * HIDC + c] +
                                 P.Snode[(size_t)P.eV[eB] * HIDC + c]) -
                            a * a * P.h[(size_t)eB * HIDC + c] + bc;
                vB[it] = val; accB += val; acc2B += val * val;
            } else vB[it] = 0.f;
        }
        P.partial [cA * HIDC + c] = accA;
        P.partial2[cA * HIDC + c] = acc2A;
        P.partial [cB * HIDC + c] = accB;
        P.partial2[cB * HIDC + c] = acc2B;
    }
    GSYNC();

    // ---- phase 2: quarter-sequential combine (bitwise == baseline kRed2) ----
    // blocks 0-3: partial quarters 0-3; blocks 4-7: partial2 quarters 0-3.
    // Strictly sequential accumulator per channel preserves rounding order.
    if (b < 8 && t < HIDC) {
        int q = b & 3;
        const float* src = ((b & 4) ? P.partial2 : P.partial) +
                           (size_t)q * (CHAINS / 4) * HIDC + t;
        float acc = 0.f;
        for (int r = 0; r < CHAINS / 4; r++) acc += src[(size_t)r * HIDC];
        P.miniP[b * HIDC + t] = acc;
    }
    GSYNC();

    // ---- phase 3: replicated mu/var + batchnorm + relu + dot(W2) -> z ----
    {
        float Ef = (float)E;
        float mu = (((P.miniP[0 * HIDC + c] + P.miniP[1 * HIDC + c]) +
                     P.miniP[2 * HIDC + c]) + P.miniP[3 * HIDC + c]) / Ef;
        float m2 = (((P.miniP[4 * HIDC + c] + P.miniP[5 * HIDC + c]) +
                     P.miniP[6 * HIDC + c]) + P.miniP[7 * HIDC + c]) / Ef;
        float rs = rsqrtf(m2 - mu * mu + 1e-5f);
        float gc = P.gamma1[c], be = P.beta1[c], wc = P.W2[c];
#pragma unroll
        for (int it = 0; it < VMAX; it++) {
            int eA = cA + it * CHAINS;   // wave-uniform guard
            if (eA < E) {
                float tt = gc * (vA[it] - mu) * rs + be;
                tt = tt > 0.f ? tt : 0.f;
                float p = tt * wc;
#pragma unroll
                for (int o = 32; o > 0; o >>= 1) p += __shfl_down(p, o, 64);
                if (c == 0) P.z[eA] = p;
            }
            int eB = cB + it * CHAINS;
            if (eB < E) {
                float tt = gc * (vB[it] - mu) * rs + be;
                tt = tt > 0.f ? tt : 0.f;
                float p = tt * wc;
#pragma unroll
                for (int o = 32; o > 0; o >>= 1) p += __shfl_down(p, o, 64);
                if (c == 0) P.z[eB] = p;
            }
        }
    }
    GSYNC();

    // ---- phase 4: S2 per node (== kS2) + minOkey init ----
    if (gtid < NND) {
        int base = gtid << 6, len = P.icnt[gtid];
        float a3 = 0.f;
        for (int j = 0; j < len; j++) {
            int e = P.ilistS[base + j];
            a3 += P.z[e] * P.dinv[e];
        }
        P.S2[gtid] = a3;
        P.minOkey[gtid] = ~0ULL;
    }
    GSYNC();

    // ---- phase 5: scores + 49-bit keys + radix pass-0 histogram ----
    for (int j = t; j < SEL_BINS; j += 256) shHist[j] = 0;
    __syncthreads();
    if (gtid < E) {
        float a = P.dinv[gtid];
        float l = a * (P.S2[P.eU[gtid]] + P.S2[P.eV[gtid]]) - a * a * P.z[gtid] +
                  P.b2[0];
        float s = 1.f / (1.f + expf(-l));
        P.score[gtid] = s;
        u32 bb = __float_as_uint(s);
        bb = (bb >> 31) ? ~bb : (bb | 0x80000000u);
        u64 key = (((u64)bb) << 17) | (u32)(0x1FFFFu - (u32)gtid);
        P.okey[gtid] = key;
        atomicAdd(&shHist[(int)((key >> 36) & (SEL_BINS - 1))], 1);
    }
    __syncthreads();
    for (int j = t; j < SEL_BINS; j += 256) {
        int vv = shHist[j];
        if (vv) atomicAdd(&P.hist[j], vv);
    }
    GSYNC();

    // ---- phases 6..8: radix-select passes 1..3 (== kHistR) ----
    for (int pass = 1; pass < 4; pass++) {
        u64 pref = selReplay(P.hist, pass, E, t, aux, shTmp);
        for (int j = t; j < SEL_BINS; j += 256) shHist[j] = 0;
        __syncthreads();
        int shift = 36 - 12 * pass;
        u64 maskHi = (~0ULL) << (shift + 12);
        if (gtid < E) {
            u64 kk = P.okey[gtid];
            if ((kk & maskHi) == pref)
                atomicAdd(&shHist[(int)((kk >> shift) & (SEL_BINS - 1))], 1);
        }
        __syncthreads();
        int* hp = P.hist + pass * SEL_BINS;
        for (int j = t; j < SEL_BINS; j += 256) {
            int vv = shHist[j];
            if (vv) atomicAdd(&hp[j], vv);
        }
        GSYNC();
    }

    // ---- phase 9: per-dst min over selected keys (== kMinKey) ----
    {
        u64 pref = selReplay(P.hist, 4, E, t, aux, shTmp);
        if (gtid < E) {
            u64 k = P.okey[gtid];
            if (k >= pref) atomicMin(&P.minOkey[P.eV[gtid]], k);
        }
    }
    GSYNC();

    // ---- phase 10: cluster assignment + member scatter (== kCluster) ----
    if (gtid < NND) {
        u64 mk = P.minOkey[gtid];
        int m = gtid;
        if (mk != ~0ULL) m = P.eU[0x1FFFFu - (u32)(mk & 0x1FFFFu)];
        P.n2c[gtid] = m;
        P.present[m] = 1;
        int slot = atomicAdd(&P.csize[m], 1);
        P.cmemb[(m << 6) + slot] = gtid;
    }
#undef GSYNC
}

// ---------------- pooled features + pooled-edge count, one dispatch --------
__global__ void kXPoolCE(const float* __restrict__ x, const int* __restrict__ n2c,
                         const int* __restrict__ o2n, const int* __restrict__ present,
                         const int* __restrict__ csize, const int* __restrict__ cmemb,
                         const int* __restrict__ ei, int* __restrict__ ni,
                         float* __restrict__ dout, int* __restrict__ ecnt2) {
    int u = blockIdx.x;
    int c = threadIdx.x;
    int gid = u * 128 + c;
    if (gid < EUA) {
        int a = o2n[n2c[ei[gid]]], b = o2n[n2c[ei[EUA + gid]]];
        if (a != b) atomicAdd(&ecnt2[a], 1);
    }
    if (c == 0) ni[u] = o2n[n2c[u]];
    if (!present[u]) return;
    int s = csize[u];
    int base = u << 6;
    float acc = 0.f;
    for (int j = 0; j < s; j++)
        acc += x[(size_t)cmemb[base + j] * ICH + c];
    dout[(size_t)o2n[u] * ICH + c] = acc / (float)s;
}

// ---------------- pooled edges ----------------
__global__ void kCEscatter(const int* __restrict__ ei, const int* __restrict__ ni,
                           const int* __restrict__ eoff2, int* __restrict__ etmp2,
                           int* __restrict__ bkD) {
    int i = blockIdx.x * 256 + threadIdx.x;
    if (i >= EUA) return;
    int a = ni[ei[i]], b = ni[ei[EUA + i]];
    if (a != b) {
        int p = eoff2[a] + atomicAdd(&etmp2[a], 1);
        bkD[p] = b;
    }
}
// variable-offset rank sort (pooled-edge buckets, avg ~16)
__global__ void kRankSort(const int* __restrict__ in, int* __restrict__ out,
                          const int* __restrict__ offA, int* __restrict__ ucnt) {
    int a = blockIdx.x;
    int s = offA[a], e = offA[a + 1], len = e - s;
    for (int j = threadIdx.x; j < len; j += 64) {
        int v = in[s + j];
        int r = 0;
        for (int i = 0; i < len; i++) {
            int w = in[s + i];
            r += (w < v) || (w == v && i < j);
        }
        out[s + r] = v;
    }
    __syncthreads();
    int c = 0;
    for (int j = threadIdx.x; j < len; j += 64)
        c += (j == 0) || (out[s + j] != out[s + j - 1]);
#pragma unroll
    for (int o = 32; o > 0; o >>= 1) c += __shfl_down(c, o, 64);
    if (threadIdx.x == 0) ucnt[a] = c;
}
// pooled-edge write + batch_pool + scores + ni, one dispatch
__global__ void kCEwriteTail(const int* __restrict__ bkD2, const int* __restrict__ eoff2,
                             const int* __restrict__ ueoff, const int* __restrict__ scal,
                             const int* __restrict__ batch, const int* __restrict__ present,
                             const int* __restrict__ o2n, const float* __restrict__ score,
                             const int* __restrict__ ni, float* __restrict__ dout) {
    int i = blockIdx.x * 256 + threadIdx.x;
    int E = scal[0], M = scal[2], Ep = scal[3];
    size_t base = (size_t)M * ICH;
    if (i < NND) {
        int s = eoff2[i], e = eoff2[i + 1];
        float* r0 = dout + base;
        float* r1 = r0 + Ep;
        int o = ueoff[i];
        for (int j = s; j < e; j++)
            if (j == s || bkD2[j] != bkD2[j - 1]) {
                r0[o] = (float)i;
                r1[o] = (float)bkD2[j];
                o++;
            }
    }
    size_t tb = base + 2 * (size_t)Ep;
    if (i < NND && present[i]) dout[tb + o2n[i]] = (float)batch[i];
    if (i < E) dout[tb + M + i] = score[i];
    if (i < NND) dout[tb + M + E + i] = (float)ni[i];
}

extern "C" void kernel_launch(void* const* d_in, const int* in_sizes, int n_in,
                              void* d_out, int out_size, void* d_ws, size_t ws_size,
                              hipStream_t stream) {
    (void)in_sizes; (void)n_in; (void)ws_size; (void)out_size;
    const float* x = (const float*)d_in[0];
    const float* W1 = (const float*)d_in[1];
    const float* b1 = (const float*)d_in[2];
    const float* gamma1 = (const float*)d_in[3];
    const float* beta1 = (const float*)d_in[4];
    const float* W2 = (const float*)d_in[5];
    const float* b2 = (const float*)d_in[6];
    const int* ei = (const int*)d_in[7];
    const int* batch = (const int*)d_in[8];
    float* dout = (float*)d_out;

    char* w = (char*)d_ws;
    size_t off = 0;
    auto carve = [&](size_t bytes) -> void* {
        off = (off + 255) & ~(size_t)255;
        void* p = w + off;
        off += bytes;
        return p;
    };
    // ---- contiguous zero-init region (ONE memset) ----
    char* zero0 = w;
    int* cnt = (int*)carve(NND * 4);
    int* itmp = (int*)carve(NND * 4);
    int* icnt = (int*)carve(NND * 4);
    int* present = (int*)carve(NND * 4);
    int* csize = (int*)carve(NND * 4);
    int* ecnt2 = (int*)carve(NND * 4);
    int* etmp2 = (int*)carve(NND * 4);
    int* scal = (int*)carve(16 * 4);
    int* hist4 = (int*)carve((size_t)4 * SEL_BINS * 4);  // one buffer per pass
    int* gbar = (int*)carve(64 * 4);                     // grid barrier counter
    size_t zeroBytes = off;
    // ---- rest ----
    int* ucnt = (int*)carve(NND * 4);
    int* uoff = (int*)carve((NND + 2) * 4);
    int* bsums = (int*)carve((NSCAN_B + 2) * 4);
    int* n2c = (int*)carve(NND * 4);
    int* o2n = (int*)carve((NND + 2) * 4);
    int* niArr = (int*)carve(NND * 4);
    int* eoff2 = (int*)carve((NND + 2) * 4);
    int* uecnt = (int*)carve(NND * 4);
    int* ueoff = (int*)carve((NND + 2) * 4);
    int* bucketV = (int*)carve((size_t)NND * BK64 * 4);  // later reused: cmemb
    int* bucketS = (int*)carve((size_t)NND * BK64 * 4);
    int* eU = (int*)carve(EFE * 4);
    int* eV = (int*)carve(EFE * 4);
    int* ilist = (int*)carve((size_t)NND * BK64 * 4);
    int* ilistS = (int*)carve((size_t)NND * BK64 * 4);
    int* bkD = (int*)carve(EUA * 4);
    int* bkD2 = (int*)carve(EUA * 4);
    u64* okey = (u64*)carve(EFE * 8);
    u64* minOkey = (u64*)carve(NND * 8);
    float* dinv = (float*)carve(EFE * 4);
    float* h = (float*)carve((size_t)EFE * HIDC * 4);
    float* Snode = (float*)carve((size_t)NND * HIDC * 4);
    float* partial = (float*)carve((size_t)CHAINS * HIDC * 4);
    float* partial2 = (float*)carve((size_t)CHAINS * HIDC * 4);
    float* miniP = (float*)carve(8 * HIDC * 4);
    float* zArr = (float*)carve(EFE * 4);
    float* S2 = (float*)carve(NND * 4);
    float* score = (float*)carve(EFE * 4);

    auto scan = [&](const int* in, int* outp, int* totalDst) {
        kScanA<<<NSCAN_B, SCAN_BS, 0, stream>>>(in, outp, bsums, NND);
        kScanB<<<NSCAN_B, SCAN_BS, 0, stream>>>(outp, bsums, NND, NSCAN_B, totalDst);
    };

    // zero scratch (one memset). d_out needs NO zeroing.
    hipMemsetAsync(zero0, 0, zeroBytes, stream);

    // clean edge list: direct stride-64 buckets -> rank-sort -> compact
    kFilterScatter64<<<NB_EU, 256, 0, stream>>>(ei, cnt, bucketV);
    kRankSort64<<<NND, 64, 0, stream>>>(bucketV, bucketS, cnt, ucnt);
    scan(ucnt, uoff, scal + 0);  // scal[0] = E
    kCompactInc<<<NB_N, 256, 0, stream>>>(bucketS, cnt, uoff, eU, eV, icnt);

    // incidence (stride-64) + dinv
    kIncScatterDinv64<<<NB_EF, 256, 0, stream>>>(eU, eV, scal, itmp, ilist, icnt, dinv);
    kRankSort64<<<NND, 64, 0, stream>>>(ilist, ilistS, icnt, ucnt);  // ucnt = dummy

    // conv1 GEMM
    kGemm<<<(EFE + GEB - 1) / GEB, 256, 0, stream>>>(x, W1, eU, eV, scal, h);

    // fused mid-chain persistent kernel (plain launch; all 512 blocks
    // co-resident by __launch_bounds__(256,2) => no cooperative API needed)
    FParams fp;
    fp.h = h; fp.dinv = dinv; fp.icnt = icnt; fp.ilistS = ilistS;
    fp.eU = eU; fp.eV = eV;
    fp.b1 = b1; fp.gamma1 = gamma1; fp.beta1 = beta1; fp.W2 = W2; fp.b2 = b2;
    fp.scal = scal;
    fp.Snode = Snode; fp.partial = partial; fp.partial2 = partial2; fp.miniP = miniP;
    fp.z = zArr; fp.S2 = S2; fp.score = score;
    fp.okey = okey; fp.minOkey = minOkey; fp.hist = hist4;
    fp.n2c = n2c; fp.present = present; fp.csize = csize; fp.cmemb = bucketV;
    fp.bar = gbar;
    kFusedMid<<<FBLK, 256, 0, stream>>>(fp);

    scan(present, o2n, scal + 2);  // scal[2] = M

    // pooled features (gather, no atomics) + pooled-edge count, one dispatch
    kXPoolCE<<<NND, 128, 0, stream>>>(x, n2c, o2n, present, csize, bucketV, ei,
                                      niArr, dout, ecnt2);

    // pooled edges
    scan(ecnt2, eoff2, scal + 4);
    kCEscatter<<<NB_EU, 256, 0, stream>>>(ei, niArr, eoff2, etmp2, bkD);
    kRankSort<<<NND, 64, 0, stream>>>(bkD, bkD2, eoff2, uecnt);
    scan(uecnt, ueoff, scal + 3);  // scal[3] = Ep
    kCEwriteTail<<<NB_EF, 256, 0, stream>>>(bkD2, eoff2, ueoff, scal, batch, present,
                                            o2n, score, niArr, dout);
}

// Round 3
// 756.571 us; speedup vs baseline: 1.1023x; 1.1023x over previous
//
#include <hip/hip_runtime.h>
#include <stdint.h>

typedef unsigned long long u64;
typedef unsigned int u32;

#define NND 20000      // nodes
#define EUA 160000     // directed input edges (2 * E_UND)
#define EFE 80000      // max clean (undirected, deduped) edges
#define ICH 128
#define HIDC 64
#define SCAN_BS 256
#define NB_N ((NND + 255) / 256)
#define NB_EU ((EUA + 255) / 256)
#define NB_EF ((EFE + 255) / 256)
#define NSCAN_B ((NND + SCAN_BS - 1) / SCAN_BS)   // 79
#define GEB 64         // edges per gemm block
#define XS_PAD 132     // xs leading-dim pad
#define BK64 64        // fixed bucket stride (degrees Poisson(4/8), max ~25)
#define SEL_BINS 4096  // 12-bit digits, 4 passes (keys: bit48==1 always)
#define FBLK 512       // persistent grid: 2 blocks/CU on 256 CUs (all resident)
#define CHAINS 4096    // moment-reduction chains (MUST stay 4096: bitwise-
                       // identical summation order vs the verified baseline)
#define VMAX ((EFE + CHAINS - 1) / CHAINS)  // 20 edges/chain -> registers

// scal slots: 0=E, 2=M, 3=Ep, 4=Ekept, 15=dummy

// ---------------- scan (exclusive, n = NND fixed; 2-dispatch, HEAD only) ----
__global__ void kScanA(const int* __restrict__ in, int* __restrict__ out,
                       int* __restrict__ bsums, int n) {
    __shared__ int sh[SCAN_BS];
    int tid = threadIdx.x;
    int i = blockIdx.x * SCAN_BS + tid;
    int v = (i < n) ? in[i] : 0;
    sh[tid] = v;
    __syncthreads();
    for (int o = 1; o < SCAN_BS; o <<= 1) {
        int t = (tid >= o) ? sh[tid - o] : 0;
        __syncthreads();
        sh[tid] += t;
        __syncthreads();
    }
    if (i < n) out[i] = sh[tid] - v;  // exclusive within block
    if (tid == SCAN_BS - 1) bsums[blockIdx.x] = sh[tid];
}
__global__ void kScanB(int* __restrict__ out, const int* __restrict__ bsums,
                       int n, int nb, int* __restrict__ totalDst) {
    __shared__ int sh[160];
    int tid = threadIdx.x;
    if (tid <= nb) sh[tid] = (tid < nb) ? bsums[tid] : 0;
    __syncthreads();
    if (tid == 0) {
        int acc = 0;
        for (int i = 0; i < nb; i++) { int t = sh[i]; sh[i] = acc; acc += t; }
        sh[nb] = acc;
    }
    __syncthreads();
    int i = blockIdx.x * SCAN_BS + tid;
    if (i < n) out[i] += sh[blockIdx.x];
    if (i == 0) {
        int tot = sh[nb];
        out[n] = tot;
        *totalDst = tot;
    }
}

// ---------------- clean edge build (stride-64 direct buckets) ----------------
__global__ void kFilterScatter64(const int* __restrict__ ei, int* __restrict__ cnt,
                                 int* __restrict__ bucketV) {
    int i = blockIdx.x * 256 + threadIdx.x;
    if (i >= EUA) return;
    int s = ei[i], d = ei[EUA + i];
    if (s < d) {
        int p = atomicAdd(&cnt[s], 1);
        bucketV[(s << 6) + p] = d;
    }
}
// wave-parallel rank sort per fixed-stride bucket + unique count
__global__ void kRankSort64(const int* __restrict__ in, int* __restrict__ out,
                            const int* __restrict__ lenA, int* __restrict__ ucnt) {
    int a = blockIdx.x;
    int len = lenA[a];
    int base = a << 6;
    for (int j = threadIdx.x; j < len; j += 64) {
        int v = in[base + j];
        int r = 0;
        for (int i = 0; i < len; i++) {
            int w = in[base + i];
            r += (w < v) || (w == v && i < j);
        }
        out[base + r] = v;
    }
    __syncthreads();
    int c = 0;
    for (int j = threadIdx.x; j < len; j += 64)
        c += (j == 0) || (out[base + j] != out[base + j - 1]);
#pragma unroll
    for (int o = 32; o > 0; o >>= 1) c += __shfl_down(c, o, 64);
    if (threadIdx.x == 0) ucnt[a] = c;
}
// compact (stride-64 in, contiguous sorted (u,v) out) + incidence count fused
__global__ void kCompactInc(const int* __restrict__ arr, const int* __restrict__ cnt,
                            const int* __restrict__ uoff, int* __restrict__ eU,
                            int* __restrict__ eV, int* __restrict__ icnt) {
    int u = blockIdx.x * 256 + threadIdx.x;
    if (u >= NND) return;
    int s = u << 6, e = s + cnt[u], o = uoff[u];
    int myc = 0;
    for (int i = s; i < e; i++)
        if (i == s || arr[i] != arr[i - 1]) {
            int v = arr[i];
            eU[o] = u; eV[o] = v; o++;
            atomicAdd(&icnt[v], 1);
            myc++;
        }
    if (myc) atomicAdd(&icnt[u], myc);
}

// ---------------- incidence (stride-64) scatter + dinv fused ----------------
__global__ void kIncScatterDinv64(const int* __restrict__ eU, const int* __restrict__ eV,
                                  const int* __restrict__ scal, int* __restrict__ itmp,
                                  int* __restrict__ ilist, const int* __restrict__ icnt,
                                  float* __restrict__ dinv) {
    int e = blockIdx.x * 256 + threadIdx.x;
    if (e >= scal[0]) return;
    int u = eU[e], v = eV[e];
    ilist[(u << 6) + atomicAdd(&itmp[u], 1)] = e;
    ilist[(v << 6) + atomicAdd(&itmp[v], 1)] = e;
    dinv[e] = rsqrtf((float)(icnt[u] + icnt[v] - 1));
}

// ---------------- GEMM: h = (0.5*(x[u]+x[v])) @ W1 ----------------
__global__ void kGemm(const float* __restrict__ x, const float* __restrict__ W1,
                      const int* __restrict__ eU, const int* __restrict__ eV,
                      const int* __restrict__ scal, float* __restrict__ h) {
    __shared__ float W1s[ICH][HIDC];
    __shared__ float xs[GEB][XS_PAD];
    int t = threadIdx.x;
    int E = scal[0];
    int e0 = blockIdx.x * GEB;
    if (e0 >= E) return;

    {
        const float4* Wv = (const float4*)W1;
        float4* Ws = (float4*)&W1s[0][0];
        for (int i = t; i < ICH * HIDC / 4; i += 256) Ws[i] = Wv[i];
    }
    {
        int eb = t >> 2, q = t & 3;
        int e = e0 + eb;
        if (e < E) {
            int u = eU[e], v = eV[e];
            const float4* xu = (const float4*)(x + (size_t)u * ICH) + q * 8;
            const float4* xv = (const float4*)(x + (size_t)v * ICH) + q * 8;
            float* xd = &xs[eb][q * 32];
#pragma unroll
            for (int i = 0; i < 8; i++) {
                float4 a = xu[i], b = xv[i];
                xd[i * 4 + 0] = 0.5f * (a.x + b.x);
                xd[i * 4 + 1] = 0.5f * (a.y + b.y);
                xd[i * 4 + 2] = 0.5f * (a.z + b.z);
                xd[i * 4 + 3] = 0.5f * (a.w + b.w);
            }
        }
    }
    __syncthreads();

    int cg4 = (t & 15) * 4;
    int es = t >> 4;
    float a00=0,a01=0,a02=0,a03=0, a10=0,a11=0,a12=0,a13=0;
    float a20=0,a21=0,a22=0,a23=0, a30=0,a31=0,a32=0,a33=0;
#pragma unroll 4
    for (int k = 0; k < ICH; k++) {
        float4 wv = *(const float4*)&W1s[k][cg4];
        float x0 = xs[es][k], x1 = xs[es + 16][k];
        float x2 = xs[es + 32][k], x3 = xs[es + 48][k];
        a00 += x0 * wv.x; a01 += x0 * wv.y; a02 += x0 * wv.z; a03 += x0 * wv.w;
        a10 += x1 * wv.x; a11 += x1 * wv.y; a12 += x1 * wv.z; a13 += x1 * wv.w;
        a20 += x2 * wv.x; a21 += x2 * wv.y; a22 += x2 * wv.z; a23 += x2 * wv.w;
        a30 += x3 * wv.x; a31 += x3 * wv.y; a32 += x3 * wv.z; a33 += x3 * wv.w;
    }
    int e;
    e = e0 + es;
    if (e < E) *(float4*)&h[(size_t)e * HIDC + cg4] = make_float4(a00, a01, a02, a03);
    e = e0 + es + 16;
    if (e < E) *(float4*)&h[(size_t)e * HIDC + cg4] = make_float4(a10, a11, a12, a13);
    e = e0 + es + 32;
    if (e < E) *(float4*)&h[(size_t)e * HIDC + cg4] = make_float4(a20, a21, a22, a23);
    e = e0 + es + 48;
    if (e < E) *(float4*)&h[(size_t)e * HIDC + cg4] = make_float4(a30, a31, a32, a33);
}

// ---------------- radix select replay (4 passes x 12 bits) ------------------
__device__ __forceinline__ u64 selReplay(const int* __restrict__ histBase, int passes,
                                         int E, int t, int* aux, int* shTmp) {
    int kr = E / 2;
    if (kr > NND / 2) kr = NND / 2;
    if (kr < 1) kr = 1;
    u64 pref = 1ULL << 48;
    for (int q = 0; q < passes; q++) {
        int shift = 36 - 12 * q;
        const int* hq = histBase + q * SEL_BINS;
        int b[16];
        int g = 0;
#pragma unroll
        for (int j = 0; j < 16; j++) { b[j] = hq[16 * t + j]; g += b[j]; }
        aux[t] = g;
        __syncthreads();
        for (int o = 1; o < 256; o <<= 1) {
            int v = (t + o < 256) ? aux[t + o] : 0;
            __syncthreads();
            aux[t] += v;
            __syncthreads();
        }
        int suf = aux[t] - g;  // strictly-above my 16-bin group
        if (suf < kr && kr <= suf + g) {
            int cum = suf, found = 16 * t;
            for (int j = 15; j >= 0; j--) {
                int hc = b[j];
                if (cum + hc >= kr) { found = 16 * t + j; break; }
                cum += hc;
            }
            shTmp[0] = found;
            shTmp[1] = kr - cum;
        }
        __syncthreads();
        pref |= ((u64)shTmp[0]) << shift;
        kr = shTmp[1];
        __syncthreads();
    }
    return pref;
}

// ---------------- device-scope grid barrier (two-level, load-poll) ----------
// All FBLK=512 blocks co-resident (2 blocks/CU x 256 CUs). Round-2 lesson:
// RMW-polling one counter serializes at the coherence point (~48us/barrier).
// Fix: (a) arrival spread over 8 padded sub-counters (64 same-line RMWs in
// parallel, not 512 serialized); (b) last arriver of each group bumps a global
// epoch; (c) everyone POLLS with a relaxed agent-scope atomic LOAD (reads
// don't serialize) + s_sleep backoff. Counters are monotonic (no reset/ABA).
// Fences identical in placement to the round-2 correct version.
__device__ __forceinline__ void gsync(int* sub, int* ep, int b, int ph) {
    __syncthreads();
    if (threadIdx.x == 0) {
        __threadfence();                               // release: publish stores
        int old = atomicAdd(&sub[(b & 7) << 6], 1);    // padded sub-counter
        if (old == (ph << 6) + 63) {                   // last of my 64-group
            __threadfence();                           // order sub -> ep hop
            atomicAdd(ep, 1);
        }
        int tgt = (ph + 1) * 8;
        while (__hip_atomic_load(ep, __ATOMIC_RELAXED,
                                 __HIP_MEMORY_SCOPE_AGENT) < tgt)
            __builtin_amdgcn_s_sleep(8);
        __threadfence();                               // acquire
    }
    __syncthreads();
}

// ---------------- fused mid-chain + tail persistent kernel ------------------
// Replaces: kSGather, kConv1Red1, kRed2, kNormZ, kS2, kScore, kHistR x3,
// kMinKey, kCluster, scan(present), kXPoolCE, scan(ecnt2), kCEscatter,
// kRankSort, scan(uecnt), kCEwriteTail  (20 dispatches -> 1).
// All floating-point and integer orders BITWISE IDENTICAL to the verified
// multi-dispatch baseline.
struct FParams {
    const float* h; const float* dinv; const int* icnt; const int* ilistS;
    const int* eU; const int* eV;
    const float* b1; const float* gamma1; const float* beta1;
    const float* W2; const float* b2;
    int* scal;
    float* Snode; float* partial; float* partial2; float* miniP;  // miniP[8][64]
    float* z; float* S2; float* score;
    u64* okey; u64* minOkey; int* hist;  // hist: 4*SEL_BINS (pass-major)
    int* n2c; int* present; int* csize; int* cmemb;
    // tail
    const float* x; const int* ei; const int* batch;
    int* o2n; int* ni; int* ecnt2; int* etmp2; int* eoff2;
    int* uecnt; int* ueoff; int* bkD; int* bkD2; int* bsums;
    float* dout;
    int* gsub; int* gep;
};

// in-kernel scan phases (blocks 0..NSCAN_B-1), integer-identical to kScanA/B
__device__ __forceinline__ void scanAPhase(const int* in, int* out, int* bsums,
                                           int b, int t, int* shS) {
    if (b >= NSCAN_B) return;            // block-uniform branch
    int i = b * SCAN_BS + t;
    int v = (i < NND) ? in[i] : 0;
    shS[t] = v;
    __syncthreads();
    for (int o = 1; o < SCAN_BS; o <<= 1) {
        int tv = (t >= o) ? shS[t - o] : 0;
        __syncthreads();
        shS[t] += tv;
        __syncthreads();
    }
    if (i < NND) out[i] = shS[t] - v;
    if (t == SCAN_BS - 1) bsums[b] = shS[t];
}
__device__ __forceinline__ void scanBPhase(int* out, const int* bsums,
                                           int* totalDst, int b, int t, int* shS) {
    if (b >= NSCAN_B) return;
    if (t <= NSCAN_B) shS[t] = (t < NSCAN_B) ? bsums[t] : 0;
    __syncthreads();
    if (t == 0) {
        int acc = 0;
        for (int i = 0; i < NSCAN_B; i++) { int tt = shS[i]; shS[i] = acc; acc += tt; }
        shS[NSCAN_B] = acc;
    }
    __syncthreads();
    int i = b * SCAN_BS + t;
    if (i < NND) out[i] += shS[b];
    if (i == 0) {
        int tot = shS[NSCAN_B];
        out[NND] = tot;
        *totalDst = tot;
    }
}

__global__ __launch_bounds__(256, 2) void kFusedMid(FParams P) {
    __shared__ int shHist[SEL_BINS];
    __shared__ int aux[256];
    __shared__ int shTmp[2];
    __shared__ int shS[SCAN_BS];
    int t = threadIdx.x;
    int b = blockIdx.x;
    int gtid = b * 256 + t;
    int w = t >> 6, c = t & 63;
    int E = P.scal[0];
    int ph = 0;
#define GSYNC() do { gsync(P.gsub, P.gep, b, ph); ph++; } while (0)

    // ---- phase 0: Snode[n][c] = sum over incident edges (== kSGather) ----
    for (int id = gtid; id < NND * HIDC; id += FBLK * 256) {
        int n = id >> 6;                 // c stays id&63 == t&63 (stride mult of 64)
        int base = n << 6, len = P.icnt[n];
        float acc = 0.f;
        for (int j = 0; j < len; j++) {
            int ed = P.ilistS[base + j];
            acc += P.h[(size_t)ed * HIDC + c] * P.dinv[ed];
        }
        P.Snode[id] = acc;
    }
    GSYNC();

    // ---- phase 1: conv1 epilogue in regs + per-chain moments ----
    int gw = b * 4 + w;                  // 0..2047
    int cA = 2 * gw, cB = cA + 1;
    float vA[VMAX], vB[VMAX];
    {
        float bc = P.b1[c];
        float accA = 0.f, acc2A = 0.f, accB = 0.f, acc2B = 0.f;
#pragma unroll
        for (int it = 0; it < VMAX; it++) {
            int eA = cA + it * CHAINS;
            if (eA < E) {
                float a = P.dinv[eA];
                float val = a * (P.Snode[(size_t)P.eU[eA] * HIDC + c] +
                                 P.Snode[(size_t)P.eV[eA] * HIDC + c]) -
                            a * a * P.h[(size_t)eA * HIDC + c] + bc;
                vA[it] = val; accA += val; acc2A += val * val;
            } else vA[it] = 0.f;
            int eB = cB + it * CHAINS;
            if (eB < E) {
                float a = P.dinv[eB];
                float val = a * (P.Snode[(size_t)P.eU[eB] * HIDC + c] +
                                 P.Snode[(size_t)P.eV[eB] * HIDC + c]) -
                            a * a * P.h[(size_t)eB * HIDC + c] + bc;
                vB[it] = val; accB += val; acc2B += val * val;
            } else vB[it] = 0.f;
        }
        P.partial [cA * HIDC + c] = accA;
        P.partial2[cA * HIDC + c] = acc2A;
        P.partial [cB * HIDC + c] = accB;
        P.partial2[cB * HIDC + c] = acc2B;
    }
    GSYNC();

    // ---- phase 2: quarter-sequential combine (bitwise == baseline kRed2) ----
    if (b < 8 && t < HIDC) {
        int q = b & 3;
        const float* src = ((b & 4) ? P.partial2 : P.partial) +
                           (size_t)q * (CHAINS / 4) * HIDC + t;
        float acc = 0.f;
        for (int r = 0; r < CHAINS / 4; r++) acc += src[(size_t)r * HIDC];
        P.miniP[b * HIDC + t] = acc;
    }
    GSYNC();

    // ---- phase 3: replicated mu/var + batchnorm + relu + dot(W2) -> z ----
    {
        float Ef = (float)E;
        float mu = (((P.miniP[0 * HIDC + c] + P.miniP[1 * HIDC + c]) +
                     P.miniP[2 * HIDC + c]) + P.miniP[3 * HIDC + c]) / Ef;
        float m2 = (((P.miniP[4 * HIDC + c] + P.miniP[5 * HIDC + c]) +
                     P.miniP[6 * HIDC + c]) + P.miniP[7 * HIDC + c]) / Ef;
        float rs = rsqrtf(m2 - mu * mu + 1e-5f);
        float gc = P.gamma1[c], be = P.beta1[c], wc = P.W2[c];
#pragma unroll
        for (int it = 0; it < VMAX; it++) {
            int eA = cA + it * CHAINS;   // wave-uniform guard
            if (eA < E) {
                float tt = gc * (vA[it] - mu) * rs + be;
                tt = tt > 0.f ? tt : 0.f;
                float p = tt * wc;
#pragma unroll
                for (int o = 32; o > 0; o >>= 1) p += __shfl_down(p, o, 64);
                if (c == 0) P.z[eA] = p;
            }
            int eB = cB + it * CHAINS;
            if (eB < E) {
                float tt = gc * (vB[it] - mu) * rs + be;
                tt = tt > 0.f ? tt : 0.f;
                float p = tt * wc;
#pragma unroll
                for (int o = 32; o > 0; o >>= 1) p += __shfl_down(p, o, 64);
                if (c == 0) P.z[eB] = p;
            }
        }
    }
    GSYNC();

    // ---- phase 4: S2 per node (== kS2) + minOkey init ----
    if (gtid < NND) {
        int base = gtid << 6, len = P.icnt[gtid];
        float a3 = 0.f;
        for (int j = 0; j < len; j++) {
            int e = P.ilistS[base + j];
            a3 += P.z[e] * P.dinv[e];
        }
        P.S2[gtid] = a3;
        P.minOkey[gtid] = ~0ULL;
    }
    GSYNC();

    // ---- phase 5: scores + 49-bit keys + radix pass-0 histogram ----
    for (int j = t; j < SEL_BINS; j += 256) shHist[j] = 0;
    __syncthreads();
    if (gtid < E) {
        float a = P.dinv[gtid];
        float l = a * (P.S2[P.eU[gtid]] + P.S2[P.eV[gtid]]) - a * a * P.z[gtid] +
                  P.b2[0];
        float s = 1.f / (1.f + expf(-l));
        P.score[gtid] = s;
        u32 bb = __float_as_uint(s);
        bb = (bb >> 31) ? ~bb : (bb | 0x80000000u);
        u64 key = (((u64)bb) << 17) | (u32)(0x1FFFFu - (u32)gtid);
        P.okey[gtid] = key;
        atomicAdd(&shHist[(int)((key >> 36) & (SEL_BINS - 1))], 1);
    }
    __syncthreads();
    for (int j = t; j < SEL_BINS; j += 256) {
        int vv = shHist[j];
        if (vv) atomicAdd(&P.hist[j], vv);
    }
    GSYNC();

    // ---- phases 6..8: radix-select passes 1..3 (== kHistR) ----
    for (int pass = 1; pass < 4; pass++) {
        u64 pref = selReplay(P.hist, pass, E, t, aux, shTmp);
        for (int j = t; j < SEL_BINS; j += 256) shHist[j] = 0;
        __syncthreads();
        int shift = 36 - 12 * pass;
        u64 maskHi = (~0ULL) << (shift + 12);
        if (gtid < E) {
            u64 kk = P.okey[gtid];
            if ((kk & maskHi) == pref)
                atomicAdd(&shHist[(int)((kk >> shift) & (SEL_BINS - 1))], 1);
        }
        __syncthreads();
        int* hp = P.hist + pass * SEL_BINS;
        for (int j = t; j < SEL_BINS; j += 256) {
            int vv = shHist[j];
            if (vv) atomicAdd(&hp[j], vv);
        }
        GSYNC();
    }

    // ---- phase 9: per-dst min over selected keys (== kMinKey) ----
    {
        u64 pref = selReplay(P.hist, 4, E, t, aux, shTmp);
        if (gtid < E) {
            u64 k = P.okey[gtid];
            if (k >= pref) atomicMin(&P.minOkey[P.eV[gtid]], k);
        }
    }
    GSYNC();

    // ---- phase 10: cluster assignment + member scatter (== kCluster) ----
    if (gtid < NND) {
        u64 mk = P.minOkey[gtid];
        int m = gtid;
        if (mk != ~0ULL) m = P.eU[0x1FFFFu - (u32)(mk & 0x1FFFFu)];
        P.n2c[gtid] = m;
        P.present[m] = 1;
        int slot = atomicAdd(&P.csize[m], 1);
        P.cmemb[(m << 6) + slot] = gtid;
    }
    GSYNC();

    // ================= fused tail =================
    // ---- T1: scan(present) -> o2n, scal[2]=M ----
    scanAPhase(P.present, P.o2n, P.bsums, b, t, shS);
    GSYNC();
    scanBPhase(P.o2n, P.bsums, P.scal + 2, b, t, shS);
    GSYNC();

    // ---- T2: pooled features (== kXPoolCE) + pooled-edge count + ni ----
    for (int i = gtid; i < EUA; i += FBLK * 256) {
        int a2 = P.o2n[P.n2c[P.ei[i]]];
        int b2 = P.o2n[P.n2c[P.ei[EUA + i]]];
        if (a2 != b2) atomicAdd(&P.ecnt2[a2], 1);
    }
    {
        int slot = t >> 7;               // 2 nodes per block-iteration
        int cc = t & 127;
        for (int u = b * 2 + slot; u < NND; u += FBLK * 2) {
            if (cc == 0) P.ni[u] = P.o2n[P.n2c[u]];
            if (P.present[u]) {
                int s = P.csize[u];
                int base2 = u << 6;
                float acc = 0.f;
                for (int j = 0; j < s; j++)
                    acc += P.x[(size_t)P.cmemb[base2 + j] * ICH + cc];
                P.dout[(size_t)P.o2n[u] * ICH + cc] = acc / (float)s;
            }
        }
    }
    GSYNC();

    // ---- T3: scan(ecnt2) -> eoff2 ----
    scanAPhase(P.ecnt2, P.eoff2, P.bsums, b, t, shS);
    GSYNC();
    scanBPhase(P.eoff2, P.bsums, P.scal + 4, b, t, shS);
    GSYNC();

    // ---- T4: pooled-edge scatter (== kCEscatter) ----
    for (int i = gtid; i < EUA; i += FBLK * 256) {
        int a2 = P.ni[P.ei[i]], b2 = P.ni[P.ei[EUA + i]];
        if (a2 != b2) {
            int p2 = P.eoff2[a2] + atomicAdd(&P.etmp2[a2], 1);
            P.bkD[p2] = b2;
        }
    }
    GSYNC();

    // ---- T5: per-wave rank sort of pooled buckets (== kRankSort) ----
    // in-wave store->load ordering via explicit vmcnt(0) (the 64-thread
    // original's __syncthreads provided exactly this: waitcnt + lockstep).
    for (int a2 = b * 4 + w; a2 < NND; a2 += FBLK * 4) {
        int s = P.eoff2[a2], eE = P.eoff2[a2 + 1], len = eE - s;
        for (int j = c; j < len; j += 64) {
            int vv = P.bkD[s + j];
            int r = 0;
            for (int i = 0; i < len; i++) {
                int ww = P.bkD[s + i];
                r += (ww < vv) || (ww == vv && i < j);
            }
            P.bkD2[s + r] = vv;
        }
        asm volatile("s_waitcnt vmcnt(0)" ::: "memory");
        int cc2 = 0;
        for (int j = c; j < len; j += 64)
            cc2 += (j == 0) || (P.bkD2[s + j] != P.bkD2[s + j - 1]);
#pragma unroll
        for (int o = 32; o > 0; o >>= 1) cc2 += __shfl_down(cc2, o, 64);
        if (c == 0) P.uecnt[a2] = cc2;
    }
    GSYNC();

    // ---- T6: scan(uecnt) -> ueoff, scal[3]=Ep ----
    scanAPhase(P.uecnt, P.ueoff, P.bsums, b, t, shS);
    GSYNC();
    scanBPhase(P.ueoff, P.bsums, P.scal + 3, b, t, shS);
    GSYNC();

    // ---- T7: pooled-edge write + batch_pool + scores + ni (== kCEwriteTail) --
    {
        int M = P.scal[2], Ep = P.scal[3];
        size_t base3 = (size_t)M * ICH;
        int bound = (E > NND) ? E : NND;
        for (int i = gtid; i < bound; i += FBLK * 256) {
            if (i < NND) {
                int s = P.eoff2[i], e2 = P.eoff2[i + 1];
                float* r0 = P.dout + base3;
                float* r1 = r0 + Ep;
                int o = P.ueoff[i];
                for (int j = s; j < e2; j++)
                    if (j == s || P.bkD2[j] != P.bkD2[j - 1]) {
                        r0[o] = (float)i;
                        r1[o] = (float)P.bkD2[j];
                        o++;
                    }
            }
            size_t tb = base3 + 2 * (size_t)Ep;
            if (i < NND && P.present[i]) P.dout[tb + P.o2n[i]] = (float)P.batch[i];
            if (i < E) P.dout[tb + M + i] = P.score[i];
            if (i < NND) P.dout[tb + M + E + i] = (float)P.ni[i];
        }
    }
#undef GSYNC
}

extern "C" void kernel_launch(void* const* d_in, const int* in_sizes, int n_in,
                              void* d_out, int out_size, void* d_ws, size_t ws_size,
                              hipStream_t stream) {
    (void)in_sizes; (void)n_in; (void)ws_size; (void)out_size;
    const float* x = (const float*)d_in[0];
    const float* W1 = (const float*)d_in[1];
    const float* b1 = (const float*)d_in[2];
    const float* gamma1 = (const float*)d_in[3];
    const float* beta1 = (const float*)d_in[4];
    const float* W2 = (const float*)d_in[5];
    const float* b2 = (const float*)d_in[6];
    const int* ei = (const int*)d_in[7];
    const int* batch = (const int*)d_in[8];
    float* dout = (float*)d_out;

    char* w = (char*)d_ws;
    size_t off = 0;
    auto carve = [&](size_t bytes) -> void* {
        off = (off + 255) & ~(size_t)255;
        void* p = w + off;
        off += bytes;
        return p;
    };
    // ---- contiguous zero-init region (ONE memset) ----
    char* zero0 = w;
    int* cnt = (int*)carve(NND * 4);
    int* itmp = (int*)carve(NND * 4);
    int* icnt = (int*)carve(NND * 4);
    int* present = (int*)carve(NND * 4);
    int* csize = (int*)carve(NND * 4);
    int* ecnt2 = (int*)carve(NND * 4);
    int* etmp2 = (int*)carve(NND * 4);
    int* scal = (int*)carve(16 * 4);
    int* hist4 = (int*)carve((size_t)4 * SEL_BINS * 4);  // one buffer per pass
    int* gsub = (int*)carve(8 * 64 * 4);                 // padded sub-counters
    int* gep = (int*)carve(64 * 4);                      // global epoch
    size_t zeroBytes = off;
    // ---- rest ----
    int* ucnt = (int*)carve(NND * 4);
    int* uoff = (int*)carve((NND + 2) * 4);
    int* bsums = (int*)carve((NSCAN_B + 2) * 4);
    int* n2c = (int*)carve(NND * 4);
    int* o2n = (int*)carve((NND + 2) * 4);
    int* niArr = (int*)carve(NND * 4);
    int* eoff2 = (int*)carve((NND + 2) * 4);
    int* uecnt = (int*)carve(NND * 4);
    int* ueoff = (int*)carve((NND + 2) * 4);
    int* bucketV = (int*)carve((size_t)NND * BK64 * 4);  // later reused: cmemb
    int* bucketS = (int*)carve((size_t)NND * BK64 * 4);
    int* eU = (int*)carve(EFE * 4);
    int* eV = (int*)carve(EFE * 4);
    int* ilist = (int*)carve((size_t)NND * BK64 * 4);
    int* ilistS = (int*)carve((size_t)NND * BK64 * 4);
    int* bkD = (int*)carve(EUA * 4);
    int* bkD2 = (int*)carve(EUA * 4);
    u64* okey = (u64*)carve(EFE * 8);
    u64* minOkey = (u64*)carve(NND * 8);
    float* dinv = (float*)carve(EFE * 4);
    float* h = (float*)carve((size_t)EFE * HIDC * 4);
    float* Snode = (float*)carve((size_t)NND * HIDC * 4);
    float* partial = (float*)carve((size_t)CHAINS * HIDC * 4);
    float* partial2 = (float*)carve((size_t)CHAINS * HIDC * 4);
    float* miniP = (float*)carve(8 * HIDC * 4);
    float* zArr = (float*)carve(EFE * 4);
    float* S2 = (float*)carve(NND * 4);
    float* score = (float*)carve(EFE * 4);

    // zero scratch (one memset). d_out needs NO zeroing.
    hipMemsetAsync(zero0, 0, zeroBytes, stream);

    // clean edge list: direct stride-64 buckets -> rank-sort -> compact
    kFilterScatter64<<<NB_EU, 256, 0, stream>>>(ei, cnt, bucketV);
    kRankSort64<<<NND, 64, 0, stream>>>(bucketV, bucketS, cnt, ucnt);
    kScanA<<<NSCAN_B, SCAN_BS, 0, stream>>>(ucnt, uoff, bsums, NND);
    kScanB<<<NSCAN_B, SCAN_BS, 0, stream>>>(uoff, bsums, NND, NSCAN_B, scal + 0);
    kCompactInc<<<NB_N, 256, 0, stream>>>(bucketS, cnt, uoff, eU, eV, icnt);

    // incidence (stride-64) + dinv
    kIncScatterDinv64<<<NB_EF, 256, 0, stream>>>(eU, eV, scal, itmp, ilist, icnt, dinv);
    kRankSort64<<<NND, 64, 0, stream>>>(ilist, ilistS, icnt, ucnt);  // ucnt = dummy

    // conv1 GEMM
    kGemm<<<(EFE + GEB - 1) / GEB, 256, 0, stream>>>(x, W1, eU, eV, scal, h);

    // fused mid-chain + tail persistent kernel
    FParams fp;
    fp.h = h; fp.dinv = dinv; fp.icnt = icnt; fp.ilistS = ilistS;
    fp.eU = eU; fp.eV = eV;
    fp.b1 = b1; fp.gamma1 = gamma1; fp.beta1 = beta1; fp.W2 = W2; fp.b2 = b2;
    fp.scal = scal;
    fp.Snode = Snode; fp.partial = partial; fp.partial2 = partial2; fp.miniP = miniP;
    fp.z = zArr; fp.S2 = S2; fp.score = score;
    fp.okey = okey; fp.minOkey = minOkey; fp.hist = hist4;
    fp.n2c = n2c; fp.present = present; fp.csize = csize; fp.cmemb = bucketV;
    fp.x = x; fp.ei = ei; fp.batch = batch;
    fp.o2n = o2n; fp.ni = niArr; fp.ecnt2 = ecnt2; fp.etmp2 = etmp2;
    fp.eoff2 = eoff2; fp.uecnt = uecnt; fp.ueoff = ueoff;
    fp.bkD = bkD; fp.bkD2 = bkD2; fp.bsums = bsums;
    fp.dout = dout;
    fp.gsub = gsub; fp.gep = gep;
    kFusedMid<<<FBLK, 256, 0, stream>>>(fp);
}

// Round 4
// 470.851 us; speedup vs baseline: 1.7713x; 1.6068x over previous
//
#include <hip/hip_runtime.h>
#include <stdint.h>

typedef unsigned long long u64;
typedef unsigned int u32;

#define NND 20000      // nodes
#define EUA 160000     // directed input edges (2 * E_UND)
#define EFE 80000      // max clean (undirected, deduped) edges
#define ICH 128
#define HIDC 64
#define SCAN_BS 256
#define NB_N ((NND + 255) / 256)
#define NB_EU ((EUA + 255) / 256)
#define NB_EF ((EFE + 255) / 256)
#define NSCAN_B ((NND + SCAN_BS - 1) / SCAN_BS)   // 79
#define PRE_N (NSCAN_B + 1)                       // 80
#define GEB 64         // edges per gemm block
#define XS_PAD 132     // xs leading-dim pad
#define BK64 64        // fixed bucket stride (degrees Poisson(4/8), max ~25)
#define SEL_BINS 4096  // 12-bit digits, 4 passes (keys: bit48==1 always)
#define FBLK 512       // persistent grid: 2 blocks/CU on 256 CUs (all resident)
#define SLOTI 16       // ints per barrier arrival slot (64 B padding)
#define CHAINS 4096    // moment-reduction chains (MUST stay 4096: bitwise-
                       // identical summation order vs the verified baseline)
#define VMAX ((EFE + CHAINS - 1) / CHAINS)  // 20 edges/chain -> registers

// ---------------- agent-coherent (MALL) access helpers ----------------------
// sc1 stores complete at the Infinity Cache (the cross-XCD coherence point),
// so NO buffer_wbl2/buffer_inv fences are ever needed. Reads stay plain+cached:
// kernel start invalidates L1/L2, and each communicated array is first
// plain-read only AFTER its sc1 writes completed (first-touch fill is fresh).
__device__ __forceinline__ int devLoadI(const int* p) {
    return __hip_atomic_load(p, __ATOMIC_RELAXED, __HIP_MEMORY_SCOPE_AGENT);
}
__device__ __forceinline__ void devStoreI(int* p, int v) {
    __hip_atomic_store(p, v, __ATOMIC_RELAXED, __HIP_MEMORY_SCOPE_AGENT);
}
__device__ __forceinline__ void devStoreF(float* p, float v) {
    __hip_atomic_store(p, v, __ATOMIC_RELAXED, __HIP_MEMORY_SCOPE_AGENT);
}
__device__ __forceinline__ void devStoreU64(u64* p, u64 v) {
    __hip_atomic_store(p, v, __ATOMIC_RELAXED, __HIP_MEMORY_SCOPE_AGENT);
}

// ---------------- scan (exclusive; HEAD dispatches only) --------------------
__global__ void kScanA(const int* __restrict__ in, int* __restrict__ out,
                       int* __restrict__ bsums, int n) {
    __shared__ int sh[SCAN_BS];
    int tid = threadIdx.x;
    int i = blockIdx.x * SCAN_BS + tid;
    int v = (i < n) ? in[i] : 0;
    sh[tid] = v;
    __syncthreads();
    for (int o = 1; o < SCAN_BS; o <<= 1) {
        int t = (tid >= o) ? sh[tid - o] : 0;
        __syncthreads();
        sh[tid] += t;
        __syncthreads();
    }
    if (i < n) out[i] = sh[tid] - v;  // exclusive within block
    if (tid == SCAN_BS - 1) bsums[blockIdx.x] = sh[tid];
}
__global__ void kScanB(int* __restrict__ out, const int* __restrict__ bsums,
                       int n, int nb, int* __restrict__ totalDst) {
    __shared__ int sh[160];
    int tid = threadIdx.x;
    if (tid <= nb) sh[tid] = (tid < nb) ? bsums[tid] : 0;
    __syncthreads();
    if (tid == 0) {
        int acc = 0;
        for (int i = 0; i < nb; i++) { int t = sh[i]; sh[i] = acc; acc += t; }
        sh[nb] = acc;
    }
    __syncthreads();
    int i = blockIdx.x * SCAN_BS + tid;
    if (i < n) out[i] += sh[blockIdx.x];
    if (i == 0) {
        int tot = sh[nb];
        out[n] = tot;
        *totalDst = tot;
    }
}

// ---------------- clean edge build (stride-64 direct buckets) ----------------
__global__ void kFilterScatter64(const int* __restrict__ ei, int* __restrict__ cnt,
                                 int* __restrict__ bucketV) {
    int i = blockIdx.x * 256 + threadIdx.x;
    if (i >= EUA) return;
    int s = ei[i], d = ei[EUA + i];
    if (s < d) {
        int p = atomicAdd(&cnt[s], 1);
        bucketV[(s << 6) + p] = d;
    }
}
__global__ void kRankSort64(const int* __restrict__ in, int* __restrict__ out,
                            const int* __restrict__ lenA, int* __restrict__ ucnt) {
    int a = blockIdx.x;
    int len = lenA[a];
    int base = a << 6;
    for (int j = threadIdx.x; j < len; j += 64) {
        int v = in[base + j];
        int r = 0;
        for (int i = 0; i < len; i++) {
            int w = in[base + i];
            r += (w < v) || (w == v && i < j);
        }
        out[base + r] = v;
    }
    __syncthreads();
    int c = 0;
    for (int j = threadIdx.x; j < len; j += 64)
        c += (j == 0) || (out[base + j] != out[base + j - 1]);
#pragma unroll
    for (int o = 32; o > 0; o >>= 1) c += __shfl_down(c, o, 64);
    if (threadIdx.x == 0) ucnt[a] = c;
}
__global__ void kCompactInc(const int* __restrict__ arr, const int* __restrict__ cnt,
                            const int* __restrict__ uoff, int* __restrict__ eU,
                            int* __restrict__ eV, int* __restrict__ icnt) {
    int u = blockIdx.x * 256 + threadIdx.x;
    if (u >= NND) return;
    int s = u << 6, e = s + cnt[u], o = uoff[u];
    int myc = 0;
    for (int i = s; i < e; i++)
        if (i == s || arr[i] != arr[i - 1]) {
            int v = arr[i];
            eU[o] = u; eV[o] = v; o++;
            atomicAdd(&icnt[v], 1);
            myc++;
        }
    if (myc) atomicAdd(&icnt[u], myc);
}

// ---------------- incidence (stride-64) scatter + dinv fused ----------------
__global__ void kIncScatterDinv64(const int* __restrict__ eU, const int* __restrict__ eV,
                                  const int* __restrict__ scal, int* __restrict__ itmp,
                                  int* __restrict__ ilist, const int* __restrict__ icnt,
                                  float* __restrict__ dinv) {
    int e = blockIdx.x * 256 + threadIdx.x;
    if (e >= scal[0]) return;
    int u = eU[e], v = eV[e];
    ilist[(u << 6) + atomicAdd(&itmp[u], 1)] = e;
    ilist[(v << 6) + atomicAdd(&itmp[v], 1)] = e;
    dinv[e] = rsqrtf((float)(icnt[u] + icnt[v] - 1));
}

// ---------------- GEMM: h = (0.5*(x[u]+x[v])) @ W1 ----------------
__global__ void kGemm(const float* __restrict__ x, const float* __restrict__ W1,
                      const int* __restrict__ eU, const int* __restrict__ eV,
                      const int* __restrict__ scal, float* __restrict__ h) {
    __shared__ float W1s[ICH][HIDC];
    __shared__ float xs[GEB][XS_PAD];
    int t = threadIdx.x;
    int E = scal[0];
    int e0 = blockIdx.x * GEB;
    if (e0 >= E) return;

    {
        const float4* Wv = (const float4*)W1;
        float4* Ws = (float4*)&W1s[0][0];
        for (int i = t; i < ICH * HIDC / 4; i += 256) Ws[i] = Wv[i];
    }
    {
        int eb = t >> 2, q = t & 3;
        int e = e0 + eb;
        if (e < E) {
            int u = eU[e], v = eV[e];
            const float4* xu = (const float4*)(x + (size_t)u * ICH) + q * 8;
            const float4* xv = (const float4*)(x + (size_t)v * ICH) + q * 8;
            float* xd = &xs[eb][q * 32];
#pragma unroll
            for (int i = 0; i < 8; i++) {
                float4 a = xu[i], b = xv[i];
                xd[i * 4 + 0] = 0.5f * (a.x + b.x);
                xd[i * 4 + 1] = 0.5f * (a.y + b.y);
                xd[i * 4 + 2] = 0.5f * (a.z + b.z);
                xd[i * 4 + 3] = 0.5f * (a.w + b.w);
            }
        }
    }
    __syncthreads();

    int cg4 = (t & 15) * 4;
    int es = t >> 4;
    float a00=0,a01=0,a02=0,a03=0, a10=0,a11=0,a12=0,a13=0;
    float a20=0,a21=0,a22=0,a23=0, a30=0,a31=0,a32=0,a33=0;
#pragma unroll 4
    for (int k = 0; k < ICH; k++) {
        float4 wv = *(const float4*)&W1s[k][cg4];
        float x0 = xs[es][k], x1 = xs[es + 16][k];
        float x2 = xs[es + 32][k], x3 = xs[es + 48][k];
        a00 += x0 * wv.x; a01 += x0 * wv.y; a02 += x0 * wv.z; a03 += x0 * wv.w;
        a10 += x1 * wv.x; a11 += x1 * wv.y; a12 += x1 * wv.z; a13 += x1 * wv.w;
        a20 += x2 * wv.x; a21 += x2 * wv.y; a22 += x2 * wv.z; a23 += x2 * wv.w;
        a30 += x3 * wv.x; a31 += x3 * wv.y; a32 += x3 * wv.z; a33 += x3 * wv.w;
    }
    int e;
    e = e0 + es;
    if (e < E) *(float4*)&h[(size_t)e * HIDC + cg4] = make_float4(a00, a01, a02, a03);
    e = e0 + es + 16;
    if (e < E) *(float4*)&h[(size_t)e * HIDC + cg4] = make_float4(a10, a11, a12, a13);
    e = e0 + es + 32;
    if (e < E) *(float4*)&h[(size_t)e * HIDC + cg4] = make_float4(a20, a21, a22, a23);
    e = e0 + es + 48;
    if (e < E) *(float4*)&h[(size_t)e * HIDC + cg4] = make_float4(a30, a31, a32, a33);
}

// ---------------- radix select replay (4 passes x 12 bits) ------------------
__device__ __forceinline__ u64 selReplay(const int* __restrict__ histBase, int passes,
                                         int E, int t, int* aux, int* shTmp) {
    int kr = E / 2;
    if (kr > NND / 2) kr = NND / 2;
    if (kr < 1) kr = 1;
    u64 pref = 1ULL << 48;
    for (int q = 0; q < passes; q++) {
        int shift = 36 - 12 * q;
        const int* hq = histBase + q * SEL_BINS;
        int b[16];
        int g = 0;
#pragma unroll
        for (int j = 0; j < 16; j++) { b[j] = hq[16 * t + j]; g += b[j]; }
        aux[t] = g;
        __syncthreads();
        for (int o = 1; o < 256; o <<= 1) {
            int v = (t + o < 256) ? aux[t + o] : 0;
            __syncthreads();
            aux[t] += v;
            __syncthreads();
        }
        int suf = aux[t] - g;  // strictly-above my 16-bin group
        if (suf < kr && kr <= suf + g) {
            int cum = suf, found = 16 * t;
            for (int j = 15; j >= 0; j--) {
                int hc = b[j];
                if (cum + hc >= kr) { found = 16 * t + j; break; }
                cum += hc;
            }
            shTmp[0] = found;
            shTmp[1] = kr - cum;
        }
        __syncthreads();
        pref |= ((u64)shTmp[0]) << shift;
        kr = shTmp[1];
        __syncthreads();
    }
    return pref;
}

// ---------------- device-scope grid barrier: store-slots + master sweep -----
// No RMWs, no cache-maintenance fences. All sc1 stores of the preceding phase
// are drained by the explicit vmcnt(0) (hardware completion = visible at MALL).
// Arrival: each block sc1-stores its epoch to a private 64B slot. Block 0's
// 256 threads sweep all slots in parallel, then publish the global epoch.
__device__ __forceinline__ void gsync(int* slots, int* ep, int b, int tgt) {
    asm volatile("s_waitcnt vmcnt(0)" ::: "memory");
    __syncthreads();
    int t = threadIdx.x;
    if (b == 0) {
        int i0 = 1 + 2 * t, i1 = 2 + 2 * t;
        for (;;) {
            int v0 = (i0 < FBLK) ? devLoadI(slots + i0 * SLOTI) : tgt;
            int v1 = (i1 < FBLK) ? devLoadI(slots + i1 * SLOTI) : tgt;
            if (__syncthreads_and((v0 >= tgt) && (v1 >= tgt))) break;
            __builtin_amdgcn_s_sleep(1);
        }
        if (t == 0) devStoreI(ep, tgt);
        __syncthreads();
    } else {
        if (t == 0) {
            devStoreI(slots + b * SLOTI, tgt);
            while (devLoadI(ep) < tgt) __builtin_amdgcn_s_sleep(4);
        }
        __syncthreads();
    }
    asm volatile("" ::: "memory");
}

// ---------------- fused mid-chain + tail persistent kernel ------------------
struct FParams {
    const float* h; const float* dinv; const int* icnt; const int* ilistS;
    const int* eU; const int* eV;
    const float* b1; const float* gamma1; const float* beta1;
    const float* W2; const float* b2;
    int* scal;
    float* Snode; float* partial; float* partial2; float* miniP;  // miniP[8][64]
    float* z; float* S2; float* score;
    u64* okey; u64* minOkey; int* hist;  // hist: 4*SEL_BINS (pass-major)
    int* n2c; int* present; int* csize; int* cmemb;
    // tail
    const float* x; const int* ei; const int* batch;
    int* o2n; int* ni; int* ecnt2; int* etmp2; int* eoff2;
    int* uecnt; int* ueoff; int* bkD; int* bkD2;
    int* bsumsA; int* bsumsB; int* bsumsC;
    float* dout;
    int* slots; int* ep;
};

// in-kernel exclusive scan, phase A only (blocks 0..78); consumers rebuild the
// 79-entry block prefix in LDS (integer-exact == baseline scanA+scanB result).
__device__ __forceinline__ void scanAPhase(const int* in, int* rawOut, int* bsums,
                                           int b, int t, int* shS) {
    if (b >= NSCAN_B) return;            // block-uniform branch
    int i = b * SCAN_BS + t;
    int v = (i < NND) ? in[i] : 0;       // plain read (post-barrier, fresh)
    shS[t] = v;
    __syncthreads();
    for (int o = 1; o < SCAN_BS; o <<= 1) {
        int tv = (t >= o) ? shS[t - o] : 0;
        __syncthreads();
        shS[t] += tv;
        __syncthreads();
    }
    if (i <= NND) devStoreI(rawOut + i, shS[t] - v);  // covers index NND too
    if (t == SCAN_BS - 1) devStoreI(bsums + b, shS[t]);
}
__device__ __forceinline__ void buildPre(const int* bsums, int* pre, int t) {
    if (t < NSCAN_B) pre[t + 1] = bsums[t];
    if (t == 0) pre[0] = 0;
    __syncthreads();
    if (t == 0)
        for (int k = 1; k <= NSCAN_B; k++) pre[k] += pre[k - 1];
    __syncthreads();
}
__device__ __forceinline__ int scanAt(const int* raw, const int* pre, int i) {
    return raw[i] + pre[i >> 8];         // valid for 0 <= i <= NND
}

__global__ __launch_bounds__(256, 2) void kFusedMid(FParams P) {
    __shared__ int shHist[SEL_BINS];
    __shared__ int aux[256];
    __shared__ int shTmp[2];
    __shared__ int shS[SCAN_BS];
    __shared__ int preA[PRE_N];
    __shared__ int preB[PRE_N];
    __shared__ int preC[PRE_N];
    int t = threadIdx.x;
    int b = blockIdx.x;
    int gtid = b * 256 + t;
    int w = t >> 6, c = t & 63;
    int E = P.scal[0];
    int ph = 1;
#define GSYNC() do { gsync(P.slots, P.ep, b, ph); ph++; } while (0)

    // ---- phase 0: Snode[n][c] = sum over incident edges (== kSGather) ----
    for (int id = gtid; id < NND * HIDC; id += FBLK * 256) {
        int n = id >> 6;
        int base = n << 6, len = P.icnt[n];
        float acc = 0.f;
        for (int j = 0; j < len; j++) {
            int ed = P.ilistS[base + j];
            acc += P.h[(size_t)ed * HIDC + c] * P.dinv[ed];
        }
        devStoreF(P.Snode + id, acc);
    }
    GSYNC();

    // ---- phase 1: conv1 epilogue in regs + per-chain moments ----
    int gw = b * 4 + w;                  // 0..2047
    int cA = 2 * gw, cB = cA + 1;
    float vA[VMAX], vB[VMAX];
    {
        float bc = P.b1[c];
        float accA = 0.f, acc2A = 0.f, accB = 0.f, acc2B = 0.f;
#pragma unroll
        for (int it = 0; it < VMAX; it++) {
            int eA = cA + it * CHAINS;
            if (eA < E) {
                float a = P.dinv[eA];
                float val = a * (P.Snode[(size_t)P.eU[eA] * HIDC + c] +
                                 P.Snode[(size_t)P.eV[eA] * HIDC + c]) -
                            a * a * P.h[(size_t)eA * HIDC + c] + bc;
                vA[it] = val; accA += val; acc2A += val * val;
            } else vA[it] = 0.f;
            int eB = cB + it * CHAINS;
            if (eB < E) {
                float a = P.dinv[eB];
                float val = a * (P.Snode[(size_t)P.eU[eB] * HIDC + c] +
                                 P.Snode[(size_t)P.eV[eB] * HIDC + c]) -
                            a * a * P.h[(size_t)eB * HIDC + c] + bc;
                vB[it] = val; accB += val; acc2B += val * val;
            } else vB[it] = 0.f;
        }
        devStoreF(P.partial  + cA * HIDC + c, accA);
        devStoreF(P.partial2 + cA * HIDC + c, acc2A);
        devStoreF(P.partial  + cB * HIDC + c, accB);
        devStoreF(P.partial2 + cB * HIDC + c, acc2B);
    }
    GSYNC();

    // ---- phase 2: quarter-sequential combine (bitwise == baseline kRed2),
    //      loads hand-pipelined 32-deep (sequential ADD order preserved) ----
    if (b < 8 && t < HIDC) {
        int q = b & 3;
        const float* src = ((b & 4) ? P.partial2 : P.partial) +
                           (size_t)q * (CHAINS / 4) * HIDC + t;
        float acc = 0.f;
        float buf[32];
#pragma unroll
        for (int k = 0; k < 32; k++) buf[k] = src[(size_t)k * HIDC];
        for (int r = 0; r < CHAINS / 4; r += 32) {
            float nxt[32];
            if (r + 32 < CHAINS / 4) {
#pragma unroll
                for (int k = 0; k < 32; k++) nxt[k] = src[(size_t)(r + 32 + k) * HIDC];
            }
#pragma unroll
            for (int k = 0; k < 32; k++) acc += buf[k];
#pragma unroll
            for (int k = 0; k < 32; k++) buf[k] = nxt[k];
        }
        devStoreF(P.miniP + b * HIDC + t, acc);
    }
    GSYNC();

    // ---- phase 3: replicated mu/var + batchnorm + relu + dot(W2) -> z ----
    {
        float Ef = (float)E;
        float mu = (((P.miniP[0 * HIDC + c] + P.miniP[1 * HIDC + c]) +
                     P.miniP[2 * HIDC + c]) + P.miniP[3 * HIDC + c]) / Ef;
        float m2 = (((P.miniP[4 * HIDC + c] + P.miniP[5 * HIDC + c]) +
                     P.miniP[6 * HIDC + c]) + P.miniP[7 * HIDC + c]) / Ef;
        float rs = rsqrtf(m2 - mu * mu + 1e-5f);
        float gc = P.gamma1[c], be = P.beta1[c], wc = P.W2[c];
#pragma unroll
        for (int it = 0; it < VMAX; it++) {
            int eA = cA + it * CHAINS;   // wave-uniform guard
            if (eA < E) {
                float tt = gc * (vA[it] - mu) * rs + be;
                tt = tt > 0.f ? tt : 0.f;
                float p = tt * wc;
#pragma unroll
                for (int o = 32; o > 0; o >>= 1) p += __shfl_down(p, o, 64);
                if (c == 0) devStoreF(P.z + eA, p);
            }
            int eB = cB + it * CHAINS;
            if (eB < E) {
                float tt = gc * (vB[it] - mu) * rs + be;
                tt = tt > 0.f ? tt : 0.f;
                float p = tt * wc;
#pragma unroll
                for (int o = 32; o > 0; o >>= 1) p += __shfl_down(p, o, 64);
                if (c == 0) devStoreF(P.z + eB, p);
            }
        }
    }
    GSYNC();

    // ---- phase 4: S2 per node (== kS2) + minOkey init ----
    if (gtid < NND) {
        int base = gtid << 6, len = P.icnt[gtid];
        float a3 = 0.f;
        for (int j = 0; j < len; j++) {
            int e = P.ilistS[base + j];
            a3 += P.z[e] * P.dinv[e];
        }
        devStoreF(P.S2 + gtid, a3);
        devStoreU64(P.minOkey + gtid, ~0ULL);
    }
    GSYNC();

    // ---- phase 5: scores + 49-bit keys + radix pass-0 histogram ----
    for (int j = t; j < SEL_BINS; j += 256) shHist[j] = 0;
    __syncthreads();
    if (gtid < E) {
        float a = P.dinv[gtid];
        float l = a * (P.S2[P.eU[gtid]] + P.S2[P.eV[gtid]]) - a * a * P.z[gtid] +
                  P.b2[0];
        float s = 1.f / (1.f + expf(-l));
        devStoreF(P.score + gtid, s);
        u32 bb = __float_as_uint(s);
        bb = (bb >> 31) ? ~bb : (bb | 0x80000000u);
        u64 key = (((u64)bb) << 17) | (u32)(0x1FFFFu - (u32)gtid);
        devStoreU64(P.okey + gtid, key);
        atomicAdd(&shHist[(int)((key >> 36) & (SEL_BINS - 1))], 1);
    }
    __syncthreads();
    for (int j = t; j < SEL_BINS; j += 256) {
        int vv = shHist[j];
        if (vv) atomicAdd(&P.hist[j], vv);
    }
    GSYNC();

    // ---- phases 6..8: radix-select passes 1..3 (== kHistR) ----
    for (int pass = 1; pass < 4; pass++) {
        u64 pref = selReplay(P.hist, pass, E, t, aux, shTmp);
        for (int j = t; j < SEL_BINS; j += 256) shHist[j] = 0;
        __syncthreads();
        int shift = 36 - 12 * pass;
        u64 maskHi = (~0ULL) << (shift + 12);
        if (gtid < E) {
            u64 kk = P.okey[gtid];
            if ((kk & maskHi) == pref)
                atomicAdd(&shHist[(int)((kk >> shift) & (SEL_BINS - 1))], 1);
        }
        __syncthreads();
        int* hp = P.hist + pass * SEL_BINS;
        for (int j = t; j < SEL_BINS; j += 256) {
            int vv = shHist[j];
            if (vv) atomicAdd(&hp[j], vv);
        }
        GSYNC();
    }

    // ---- phase 9: per-dst min over selected keys (== kMinKey) ----
    {
        u64 pref = selReplay(P.hist, 4, E, t, aux, shTmp);
        if (gtid < E) {
            u64 k = P.okey[gtid];
            if (k >= pref) atomicMin(&P.minOkey[P.eV[gtid]], k);
        }
    }
    GSYNC();

    // ---- phase 10: cluster assignment + member scatter (== kCluster) ----
    if (gtid < NND) {
        u64 mk = P.minOkey[gtid];
        int m = gtid;
        if (mk != ~0ULL) m = P.eU[0x1FFFFu - (u32)(mk & 0x1FFFFu)];
        devStoreI(P.n2c + gtid, m);
        devStoreI(P.present + m, 1);
        int slot = atomicAdd(&P.csize[m], 1);
        devStoreI(P.cmemb + (m << 6) + slot, gtid);
    }
    GSYNC();

    // ================= fused tail =================
    // ---- T1: scanA(present) -> o2nRaw, bsumsA ----
    scanAPhase(P.present, P.o2n, P.bsumsA, b, t, shS);
    GSYNC();

    // ---- T2: pooled features + pooled-edge count + ni (uses preA) ----
    buildPre(P.bsumsA, preA, t);
    for (int i = gtid; i < EUA; i += FBLK * 256) {
        int a2 = scanAt(P.o2n, preA, P.n2c[P.ei[i]]);
        int b2 = scanAt(P.o2n, preA, P.n2c[P.ei[EUA + i]]);
        if (a2 != b2) atomicAdd(&P.ecnt2[a2], 1);
    }
    {
        int slot = t >> 7;               // 2 nodes per block-iteration
        int cc = t & 127;
        for (int u = b * 2 + slot; u < NND; u += FBLK * 2) {
            if (cc == 0) devStoreI(P.ni + u, scanAt(P.o2n, preA, P.n2c[u]));
            if (P.present[u]) {
                int s = P.csize[u];
                int base2 = u << 6;
                float acc = 0.f;
                for (int j = 0; j < s; j++)
                    acc += P.x[(size_t)P.cmemb[base2 + j] * ICH + cc];
                P.dout[(size_t)scanAt(P.o2n, preA, u) * ICH + cc] = acc / (float)s;
            }
        }
    }
    GSYNC();

    // ---- T3: scanA(ecnt2) -> eoff2Raw, bsumsB ----
    scanAPhase(P.ecnt2, P.eoff2, P.bsumsB, b, t, shS);
    GSYNC();

    // ---- T4: pooled-edge scatter (uses preB) ----
    buildPre(P.bsumsB, preB, t);
    for (int i = gtid; i < EUA; i += FBLK * 256) {
        int a2 = P.ni[P.ei[i]], b2 = P.ni[P.ei[EUA + i]];
        if (a2 != b2) {
            int p2 = scanAt(P.eoff2, preB, a2) + atomicAdd(&P.etmp2[a2], 1);
            devStoreI(P.bkD + p2, b2);
        }
    }
    GSYNC();

    // ---- T5: per-wave rank sort of pooled buckets (== kRankSort) ----
    for (int a2 = b * 4 + w; a2 < NND; a2 += FBLK * 4) {
        int s = scanAt(P.eoff2, preB, a2);
        int eE = scanAt(P.eoff2, preB, a2 + 1);
        int len = eE - s;
        for (int j = c; j < len; j += 64) {
            int vv = P.bkD[s + j];
            int r = 0;
            for (int i = 0; i < len; i++) {
                int ww = P.bkD[s + i];
                r += (ww < vv) || (ww == vv && i < j);
            }
            devStoreI(P.bkD2 + s + r, vv);
        }
        asm volatile("s_waitcnt vmcnt(0)" ::: "memory");
        int cc2 = 0;
        for (int j = c; j < len; j += 64)
            cc2 += (j == 0) || (P.bkD2[s + j] != P.bkD2[s + j - 1]);
#pragma unroll
        for (int o = 32; o > 0; o >>= 1) cc2 += __shfl_down(cc2, o, 64);
        if (c == 0) devStoreI(P.uecnt + a2, cc2);
    }
    GSYNC();

    // ---- T6: scanA(uecnt) -> ueoffRaw, bsumsC ----
    scanAPhase(P.uecnt, P.ueoff, P.bsumsC, b, t, shS);
    GSYNC();

    // ---- T7: pooled-edge write + batch_pool + scores + ni ----
    {
        buildPre(P.bsumsC, preC, t);
        int M = preA[NSCAN_B], Ep = preC[NSCAN_B];
        size_t base3 = (size_t)M * ICH;
        int bound = (E > NND) ? E : NND;
        for (int i = gtid; i < bound; i += FBLK * 256) {
            if (i < NND) {
                int s = scanAt(P.eoff2, preB, i);
                int e2 = scanAt(P.eoff2, preB, i + 1);
                float* r0 = P.dout + base3;
                float* r1 = r0 + Ep;
                int o = scanAt(P.ueoff, preC, i);
                int prev = 0;
                for (int j = s; j < e2; j++) {
                    // bkD2 lines straddle bucket boundaries -> a same-XCD L2
                    // fill during T5 can hold partially-stale neighbor bytes;
                    // read via sc1 (MALL) here.
                    int bj = devLoadI(P.bkD2 + j);
                    if (j == s || bj != prev) {
                        r0[o] = (float)i;
                        r1[o] = (float)bj;
                        o++;
                    }
                    prev = bj;
                }
            }
            size_t tb = base3 + 2 * (size_t)Ep;
            if (i < NND && P.present[i])
                P.dout[tb + scanAt(P.o2n, preA, i)] = (float)P.batch[i];
            if (i < E) P.dout[tb + M + i] = P.score[i];
            if (i < NND) P.dout[tb + M + E + i] = (float)P.ni[i];
        }
    }
#undef GSYNC
}

extern "C" void kernel_launch(void* const* d_in, const int* in_sizes, int n_in,
                              void* d_out, int out_size, void* d_ws, size_t ws_size,
                              hipStream_t stream) {
    (void)in_sizes; (void)n_in; (void)ws_size; (void)out_size;
    const float* x = (const float*)d_in[0];
    const float* W1 = (const float*)d_in[1];
    const float* b1 = (const float*)d_in[2];
    const float* gamma1 = (const float*)d_in[3];
    const float* beta1 = (const float*)d_in[4];
    const float* W2 = (const float*)d_in[5];
    const float* b2 = (const float*)d_in[6];
    const int* ei = (const int*)d_in[7];
    const int* batch = (const int*)d_in[8];
    float* dout = (float*)d_out;

    char* w = (char*)d_ws;
    size_t off = 0;
    auto carve = [&](size_t bytes) -> void* {
        off = (off + 255) & ~(size_t)255;
        void* p = w + off;
        off += bytes;
        return p;
    };
    // ---- contiguous zero-init region (ONE memset) ----
    char* zero0 = w;
    int* cnt = (int*)carve(NND * 4);
    int* itmp = (int*)carve(NND * 4);
    int* icnt = (int*)carve(NND * 4);
    int* present = (int*)carve(NND * 4);
    int* csize = (int*)carve(NND * 4);
    int* ecnt2 = (int*)carve(NND * 4);
    int* etmp2 = (int*)carve(NND * 4);
    int* scal = (int*)carve(16 * 4);
    int* hist4 = (int*)carve((size_t)4 * SEL_BINS * 4);  // one buffer per pass
    int* slots = (int*)carve((size_t)FBLK * SLOTI * 4);  // barrier slots (32 KB)
    int* gep = (int*)carve(64 * 4);                      // global epoch
    size_t zeroBytes = off;
    // ---- rest ----
    int* ucnt = (int*)carve(NND * 4);
    int* uoff = (int*)carve((NND + 2) * 4);
    int* bsumsH = (int*)carve((NSCAN_B + 2) * 4);        // head scan
    int* bsumsA = (int*)carve((NSCAN_B + 2) * 4);
    int* bsumsB = (int*)carve((NSCAN_B + 2) * 4);
    int* bsumsC = (int*)carve((NSCAN_B + 2) * 4);
    int* n2c = (int*)carve(NND * 4);
    int* o2n = (int*)carve((NND + 2) * 4);
    int* niArr = (int*)carve(NND * 4);
    int* eoff2 = (int*)carve((NND + 2) * 4);
    int* uecnt = (int*)carve(NND * 4);
    int* ueoff = (int*)carve((NND + 2) * 4);
    int* bucketV = (int*)carve((size_t)NND * BK64 * 4);  // later reused: cmemb
    int* bucketS = (int*)carve((size_t)NND * BK64 * 4);
    int* eU = (int*)carve(EFE * 4);
    int* eV = (int*)carve(EFE * 4);
    int* ilist = (int*)carve((size_t)NND * BK64 * 4);
    int* ilistS = (int*)carve((size_t)NND * BK64 * 4);
    int* bkD = (int*)carve(EUA * 4);
    int* bkD2 = (int*)carve(EUA * 4);
    u64* okey = (u64*)carve(EFE * 8);
    u64* minOkey = (u64*)carve(NND * 8);
    float* dinv = (float*)carve(EFE * 4);
    float* h = (float*)carve((size_t)EFE * HIDC * 4);
    float* Snode = (float*)carve((size_t)NND * HIDC * 4);
    float* partial = (float*)carve((size_t)CHAINS * HIDC * 4);
    float* partial2 = (float*)carve((size_t)CHAINS * HIDC * 4);
    float* miniP = (float*)carve(8 * HIDC * 4);
    float* zArr = (float*)carve(EFE * 4);
    float* S2 = (float*)carve(NND * 4);
    float* score = (float*)carve(EFE * 4);

    // zero scratch (one memset). d_out needs NO zeroing.
    hipMemsetAsync(zero0, 0, zeroBytes, stream);

    // clean edge list: direct stride-64 buckets -> rank-sort -> compact
    kFilterScatter64<<<NB_EU, 256, 0, stream>>>(ei, cnt, bucketV);
    kRankSort64<<<NND, 64, 0, stream>>>(bucketV, bucketS, cnt, ucnt);
    kScanA<<<NSCAN_B, SCAN_BS, 0, stream>>>(ucnt, uoff, bsumsH, NND);
    kScanB<<<NSCAN_B, SCAN_BS, 0, stream>>>(uoff, bsumsH, NND, NSCAN_B, scal + 0);
    kCompactInc<<<NB_N, 256, 0, stream>>>(bucketS, cnt, uoff, eU, eV, icnt);

    // incidence (stride-64) + dinv
    kIncScatterDinv64<<<NB_EF, 256, 0, stream>>>(eU, eV, scal, itmp, ilist, icnt, dinv);
    kRankSort64<<<NND, 64, 0, stream>>>(ilist, ilistS, icnt, ucnt);  // ucnt = dummy

    // conv1 GEMM
    kGemm<<<(EFE + GEB - 1) / GEB, 256, 0, stream>>>(x, W1, eU, eV, scal, h);

    // fused mid-chain + tail persistent kernel
    FParams fp;
    fp.h = h; fp.dinv = dinv; fp.icnt = icnt; fp.ilistS = ilistS;
    fp.eU = eU; fp.eV = eV;
    fp.b1 = b1; fp.gamma1 = gamma1; fp.beta1 = beta1; fp.W2 = W2; fp.b2 = b2;
    fp.scal = scal;
    fp.Snode = Snode; fp.partial = partial; fp.partial2 = partial2; fp.miniP = miniP;
    fp.z = zArr; fp.S2 = S2; fp.score = score;
    fp.okey = okey; fp.minOkey = minOkey; fp.hist = hist4;
    fp.n2c = n2c; fp.present = present; fp.csize = csize; fp.cmemb = bucketV;
    fp.x = x; fp.ei = ei; fp.batch = batch;
    fp.o2n = o2n; fp.ni = niArr; fp.ecnt2 = ecnt2; fp.etmp2 = etmp2;
    fp.eoff2 = eoff2; fp.uecnt = uecnt; fp.ueoff = ueoff;
    fp.bkD = bkD; fp.bkD2 = bkD2;
    fp.bsumsA = bsumsA; fp.bsumsB = bsumsB; fp.bsumsC = bsumsC;
    fp.dout = dout;
    fp.slots = slots; fp.ep = gep;
    kFusedMid<<<FBLK, 256, 0, stream>>>(fp);
}